// Round 8
// baseline (10191.588 us; speedup 1.0000x reference)
//
#include <hip/hip_runtime.h>
#include <hip/hip_bf16.h>
#include <hip/hip_fp16.h>
#include <stdint.h>

typedef _Float16 h2_t  __attribute__((ext_vector_type(2)));
typedef _Float16 f16x8 __attribute__((ext_vector_type(8)));
typedef float    f32x4 __attribute__((ext_vector_type(4)));

#define TSEQ 4096
#define HID  256
#define IN2  512
#define NB   64
#define CH   256
#define NCH  16

__device__ __forceinline__ h2_t bc_h2(uint32_t v){ return __builtin_bit_cast(h2_t, v); }

// quad butterfly reduce via DPP (VALU pipe, not LDS)
__device__ __forceinline__ float quad_reduce(float x){
    float t;
    t = __builtin_bit_cast(float, __builtin_amdgcn_mov_dpp(__builtin_bit_cast(int, x), 0xB1, 0xF, 0xF, true));
    x += t;
    t = __builtin_bit_cast(float, __builtin_amdgcn_mov_dpp(__builtin_bit_cast(int, x), 0x4E, 0xF, 0xF, true));
    x += t;
    return x;
}

// cheap activations (validated r6/r7: absmax unchanged)
__device__ __forceinline__ float sigm_(float x){
    return __builtin_amdgcn_rcpf(1.f + __expf(-x));
}
__device__ __forceinline__ float tanh_(float x){
    return 1.f - 2.f*__builtin_amdgcn_rcpf(1.f + __expf(2.f*x));
}

// raw barrier: LDS-ordered, does NOT drain vmcnt (global ops stay in flight)
__device__ __forceinline__ void sync_lds(){
    asm volatile("s_waitcnt lgkmcnt(0)\n\ts_barrier" ::: "memory");
}

// ---------------- prep: pack recurrent weights, transpose x-weights, emb->f16, bias ----------
__global__ void prep_kernel(const float* __restrict__ Wr, const float* __restrict__ Wz,
                            const float* __restrict__ Wh, const float* __restrict__ emb,
                            const float* __restrict__ br, const float* __restrict__ bz,
                            const float* __restrict__ bh,
                            uint32_t* __restrict__ wpack, __half* __restrict__ wxt,
                            __half* __restrict__ embf16, float* __restrict__ biasv)
{
    const long long S0 = 2LL*3*128*256;      // packed recurrent h-part weights (h2)
    const long long S1 = 2LL*768*256;        // WxT[L][o][k]
    const long long S2 = 32000LL*256;        // emb f16
    const long long S3 = 2LL*768;            // biasv[L][o]
    for (long long idx = (long long)blockIdx.x*256 + threadIdx.x; idx < S0+S1+S2+S3;
         idx += (long long)gridDim.x*256) {
        if (idx < S0) {
            int n   = (int)(idx & 255);
            int kk2 = (int)((idx >> 8) & 127);
            int t   = (int)(idx >> 15);          // 0..5 = L*3+g
            int g = t % 3, L = t / 3;
            const float* Wsrc = (g==0?Wr:(g==1?Wz:Wh)) + (size_t)L*IN2*HID;
            h2_t p;
            p[0] = (_Float16)Wsrc[(256 + 2*kk2)*HID + n];
            p[1] = (_Float16)Wsrc[(257 + 2*kk2)*HID + n];
            wpack[idx] = __builtin_bit_cast(uint32_t, p);
        } else if (idx < S0+S1) {
            int i  = (int)(idx - S0);
            int k  = i & 255;
            int i2 = i >> 8;                     // 0..1535
            int o  = i2 % 768, L = i2 / 768;
            int g  = o >> 8,   n = o & 255;
            const float* Wsrc = (g==0?Wr:(g==1?Wz:Wh)) + (size_t)L*IN2*HID;
            wxt[i] = __float2half(Wsrc[k*HID + n]);   // WxT[L][o][k]
        } else if (idx < S0+S1+S2) {
            int i = (int)(idx - S0 - S1);
            embf16[i] = __float2half(emb[i]);
        } else {
            int i = (int)(idx - S0 - S1 - S2);   // [0, 1536)
            int o = i % 768, L = i / 768;
            int g = o >> 8,  n = o & 255;
            const float* bsrc = (g==0?br:(g==1?bz:bh));
            biasv[i] = bsrc[L*HID + n];
        }
    }
}

// ---------------- x-projection GEMM (both layers in one launch via blockIdx.z) --------------
// packed proj layout: u32 word g*128+nb of a row holds (val[nb], val[nb+128]) for gate g
__global__ __launch_bounds__(256) void gemm_proj(
    const int* __restrict__ tokens, const __half* __restrict__ embf16,
    const __half* __restrict__ h0chunk, const __half* __restrict__ wxt,
    const float* __restrict__ biasv,
    __half* __restrict__ proj0, __half* __restrict__ proj1, int c0, int c1)
{
    const int Lz = blockIdx.z;
    const int c  = Lz ? c1 : c0;
    if (c < 0 || c >= NCH) return;
    __half* proj = Lz ? proj1 : proj0;

    __shared__ uint4 Ald[128*17];
    __shared__ uint4 Bld[64*17];
    const int tid = threadIdx.x;
    const int mt = blockIdx.x, nt = blockIdx.y;
    const int w = tid >> 6, l = tid & 63, lr = l & 15, lk = l >> 4;
    f32x4 acc[2][4] = {};

#pragma unroll 1
    for (int kh = 0; kh < 2; ++kh) {
        if (kh) __syncthreads();
#pragma unroll
        for (int it = 0; it < 8; ++it) {
            int idx = it*256 + tid;
            int row = idx >> 4, u4 = idx & 15;
            int grow = mt*128 + row;
            const __half* src;
            if (Lz == 0) {
                int b = grow >> 8, tl = grow & (CH-1);
                int tok = tokens[(size_t)b*TSEQ + c*CH + tl];
                src = embf16 + (size_t)tok*HID;
            } else {
                src = h0chunk + (size_t)grow*HID;
            }
            Ald[row*17 + u4] = ((const uint4*)(src + kh*128))[u4];
        }
#pragma unroll
        for (int it = 0; it < 4; ++it) {
            int idx = it*256 + tid;
            int col = idx >> 4, u4 = idx & 15;
            const __half* src = wxt + ((size_t)(Lz*768 + nt*64 + col))*HID + kh*128;
            Bld[col*17 + u4] = ((const uint4*)src)[u4];
        }
        __syncthreads();
        const _Float16* A = (const _Float16*)Ald;
        const _Float16* B = (const _Float16*)Bld;
#pragma unroll
        for (int kb = 0; kb < 4; ++kb) {
            int k0 = kb*32;
            f16x8 af[2], bf[4];
#pragma unroll
            for (int fm = 0; fm < 2; ++fm) {
                int row = w*32 + fm*16 + lr;
                af[fm] = *(const f16x8*)(A + row*136 + k0 + lk*8);
            }
#pragma unroll
            for (int fn = 0; fn < 4; ++fn) {
                int col = fn*16 + lr;
                bf[fn] = *(const f16x8*)(B + col*136 + k0 + lk*8);
            }
#pragma unroll
            for (int fm = 0; fm < 2; ++fm)
#pragma unroll
                for (int fn = 0; fn < 4; ++fn)
                    acc[fm][fn] = __builtin_amdgcn_mfma_f32_16x16x32_f16(af[fm], bf[fn], acc[fm][fn], 0,0,0);
        }
    }
#pragma unroll
    for (int fm = 0; fm < 2; ++fm)
#pragma unroll
        for (int fn = 0; fn < 4; ++fn)
#pragma unroll
            for (int q = 0; q < 4; ++q) {
                int row = mt*128 + w*32 + fm*16 + lk*4 + q;
                int col = nt*64 + fn*16 + lr;
                float v = acc[fm][fn][q] + biasv[Lz*768 + col];
                int po = ((col >> 8) << 8) + ((col & 127) << 1) + ((col >> 7) & 1);
                proj[(size_t)row*768 + po] = __float2half(v);
            }
}

// ---------------- fused recurrence: blocks 0-63 = L0 chunk c0, 64-127 = L1 chunk c1 ---------
// 1024 threads: thread (k4 = tid&3, n = tid>>2) owns ONE neuron n, 3 gates, K-quarter k4.
// 96 weight-u32/thread -> true VGPR residency (no spill pressure). 16 waves = 4/SIMD.
__global__ __launch_bounds__(1024, 4) void rec_fused(
    const uint32_t* __restrict__ wpack,
    const __half* __restrict__ proj0, const __half* __restrict__ proj1,
    __half* __restrict__ h0chunk, float* __restrict__ hstate,
    const float* __restrict__ Wfc, const float* __restrict__ bfc,
    float* __restrict__ out, int c0, int c1)
{
    __shared__ __align__(16) _Float16 s_h[256];
    __shared__ __align__(16) _Float16 s_rh[256];
    __shared__ float s_head[256];

    const int L = blockIdx.x >> 6;
    const int b = blockIdx.x & 63;
    const int c = L ? c1 : c0;
    if (c < 0 || c >= NCH) return;

    const int tid = threadIdx.x;
    const int k4  = tid & 3;
    const int n   = tid >> 2;            // [0,256)
    const bool wlead = (k4 == 0);
    const int half = n >> 7;             // proj packed-half selector
    const int nlo  = n & 127;

    // weights: 32 u32 per gate, load order permuted to match rotated LDS reads:
    // reg i = u*4+j  <->  K-h2 index  k4*32 + ((u+k4)&7)*4 + j
    uint32_t wr_[32], wz_[32], wh_[32];
    {
        const uint32_t* wb = wpack + (size_t)(L*3*128)*256;
#pragma unroll
        for (int u = 0; u < 8; ++u)
#pragma unroll
            for (int j = 0; j < 4; ++j) {
                int i  = u*4 + j;
                int kk = k4*32 + (((u + k4) & 7)*4 + j);
                wr_[i] = wb[(      kk)*256 + n];
                wz_[i] = wb[(128 + kk)*256 + n];
                wh_[i] = wb[(256 + kk)*256 + n];
            }
    }
#pragma unroll
    for (int i = 0; i < 32; ++i) {
        asm volatile("" : "+v"(wr_[i]), "+v"(wz_[i]), "+v"(wh_[i]));
    }

    float hf;
    if (c == 0) hf = 0.f;
    else        hf = hstate[(size_t)(L*NB + b)*HID + n];
    if (wlead) s_h[n] = (_Float16)hf;
    __syncthreads();

    const uint32_t* prow = (const uint32_t*)((L ? proj1 : proj0) + (size_t)b*CH*768);
    const uint4* hq4 = ((const uint4*)s_h)  + k4*8;   // quarter = 8 uint4 (128B)
    const uint4* rq4 = ((const uint4*)s_rh) + k4*8;

#pragma unroll 1
    for (int tl = 0; tl < CH; ++tl) {
        // packed proj words (issued early; raw barriers don't drain them)
        const uint32_t* pp = prow + (size_t)tl*384;
        uint32_t pj0 = pp[      nlo];
        uint32_t pj1 = pp[128 + nlo];
        uint32_t pj2 = pp[256 + nlo];

        // phase A: r,z over h; rotated b128 reads (conflict-free across k4)
        float ar0=0.f, ar1=0.f, az0=0.f, az1=0.f;
#pragma unroll
        for (int u = 0; u < 8; ++u) {
            uint4 hv = hq4[(u + k4) & 7];
            int i = u*4;
            ar0 = __builtin_amdgcn_fdot2(bc_h2(wr_[i  ]), bc_h2(hv.x), ar0, false);
            az0 = __builtin_amdgcn_fdot2(bc_h2(wz_[i  ]), bc_h2(hv.x), az0, false);
            ar1 = __builtin_amdgcn_fdot2(bc_h2(wr_[i+1]), bc_h2(hv.y), ar1, false);
            az1 = __builtin_amdgcn_fdot2(bc_h2(wz_[i+1]), bc_h2(hv.y), az1, false);
            ar0 = __builtin_amdgcn_fdot2(bc_h2(wr_[i+2]), bc_h2(hv.z), ar0, false);
            az0 = __builtin_amdgcn_fdot2(bc_h2(wz_[i+2]), bc_h2(hv.z), az0, false);
            ar1 = __builtin_amdgcn_fdot2(bc_h2(wr_[i+3]), bc_h2(hv.w), ar1, false);
            az1 = __builtin_amdgcn_fdot2(bc_h2(wz_[i+3]), bc_h2(hv.w), az1, false);
        }
        float ar = quad_reduce(ar0 + ar1);
        float az = quad_reduce(az0 + az1);

        h2_t pjr = bc_h2(pj0), pjz = bc_h2(pj1);
        float r = sigm_(ar + (float)pjr[half]);
        float z = sigm_(az + (float)pjz[half]);
        if (wlead) s_rh[n] = (_Float16)(r*hf);
        sync_lds();

        // phase B: candidate over r*h; same rotation
        float ah0=0.f, ah1=0.f;
#pragma unroll
        for (int u = 0; u < 8; ++u) {
            uint4 rv = rq4[(u + k4) & 7];
            int i = u*4;
            ah0 = __builtin_amdgcn_fdot2(bc_h2(wh_[i  ]), bc_h2(rv.x), ah0, false);
            ah1 = __builtin_amdgcn_fdot2(bc_h2(wh_[i+1]), bc_h2(rv.y), ah1, false);
            ah0 = __builtin_amdgcn_fdot2(bc_h2(wh_[i+2]), bc_h2(rv.z), ah0, false);
            ah1 = __builtin_amdgcn_fdot2(bc_h2(wh_[i+3]), bc_h2(rv.w), ah1, false);
        }
        float ah = quad_reduce(ah0 + ah1);

        h2_t pjh = bc_h2(pj2);
        float t = tanh_(ah + (float)pjh[half]);
        hf += z*(t - hf);
        if (wlead) {
            s_h[n] = (_Float16)hf;
            if (L == 0) h0chunk[((size_t)b*CH + tl)*HID + n] = __float2half(hf);
        }
        sync_lds();
    }

    if (wlead) hstate[(size_t)(L*NB + b)*HID + n] = hf;

    if (L == 1 && c == NCH-1) {
        if (wlead) s_head[n] = hf;
        __syncthreads();
        if (tid < 64) {
            float p0 = 0.f, p1 = 0.f;
#pragma unroll
            for (int m = 0; m < 4; ++m) {
                float hv2 = s_head[tid + 64*m];
                p0 += hv2 * Wfc[(tid+64*m)*2+0];
                p1 += hv2 * Wfc[(tid+64*m)*2+1];
            }
#pragma unroll
            for (int d = 1; d < 64; d <<= 1) { p0 += __shfl_xor(p0, d); p1 += __shfl_xor(p1, d); }
            if (tid == 0) { out[b*2+0] = p0 + bfc[0]; out[b*2+1] = p1 + bfc[1]; }
        }
    }
}

// ---------------- host ----------------
extern "C" void kernel_launch(void* const* d_in, const int* in_sizes, int n_in,
                              void* d_out, int out_size, void* d_ws, size_t ws_size,
                              hipStream_t stream) {
    const int*   tokens = (const int*)  d_in[0];
    const float* emb    = (const float*)d_in[1];
    const float* Wr     = (const float*)d_in[2];
    const float* br     = (const float*)d_in[3];
    const float* Wz     = (const float*)d_in[4];
    const float* bz     = (const float*)d_in[5];
    const float* Wh     = (const float*)d_in[6];
    const float* bh     = (const float*)d_in[7];
    const float* Wfc    = (const float*)d_in[8];
    const float* bfc    = (const float*)d_in[9];
    float* out = (float*)d_out;

    char* ws = (char*)d_ws;
    uint32_t* wpack  = (uint32_t*)(ws + 0);               //   786,432 B
    __half*   wxt    = (__half*)(ws + (1u<<20));          //   786,432 B
    __half*   embf16 = (__half*)(ws + (2u<<20));          // 16,384,000 B
    __half*   proj0  = (__half*)(ws + 18874368u);         // 25,165,824 B
    __half*   proj1  = (__half*)(ws + 44040192u);         // 25,165,824 B
    __half*   h0chunk= (__half*)(ws + 69206016u);         //  8,388,608 B
    float*    hstate = (float*)(ws + 77594624u);          //    131,072 B
    float*    biasv  = (float*)(ws + 77725696u);          //      6,144 B

    prep_kernel<<<2048, 256, 0, stream>>>(Wr, Wz, Wh, emb, br, bz, bh, wpack, wxt, embf16, biasv);

    dim3 ggrid(128, 12, 2);
    for (int c = 0; c <= NCH; ++c) {
        int cc0 = (c < NCH) ? c : -1;
        int cc1 = c - 1;
        gemm_proj<<<ggrid, 256, 0, stream>>>(tokens, embf16, h0chunk, wxt, biasv, proj0, proj1, cc0, cc1);
        rec_fused<<<128, 1024, 0, stream>>>(wpack, proj0, proj1, h0chunk, hstate, Wfc, bfc, out, cc0, cc1);
    }
}

// Round 9
// 7428.491 us; speedup vs baseline: 1.3720x; 1.3720x over previous
//
#include <hip/hip_runtime.h>
#include <hip/hip_bf16.h>
#include <hip/hip_fp16.h>
#include <stdint.h>

typedef _Float16 h2_t  __attribute__((ext_vector_type(2)));
typedef _Float16 f16x8 __attribute__((ext_vector_type(8)));
typedef float    f32x4 __attribute__((ext_vector_type(4)));

#define TSEQ 4096
#define HID  256
#define IN2  512
#define NB   64
#define CH   256
#define NCH  16

__device__ __forceinline__ h2_t bc_h2(uint32_t v){ return __builtin_bit_cast(h2_t, v); }

// quad butterfly reduce via DPP (VALU pipe, not LDS)
__device__ __forceinline__ float quad_reduce(float x){
    float t;
    t = __builtin_bit_cast(float, __builtin_amdgcn_mov_dpp(__builtin_bit_cast(int, x), 0xB1, 0xF, 0xF, true));
    x += t;
    t = __builtin_bit_cast(float, __builtin_amdgcn_mov_dpp(__builtin_bit_cast(int, x), 0x4E, 0xF, 0xF, true));
    x += t;
    return x;
}

// cheap activations (validated r6/r7: absmax unchanged)
__device__ __forceinline__ float sigm_(float x){
    return __builtin_amdgcn_rcpf(1.f + __expf(-x));
}
__device__ __forceinline__ float tanh_(float x){
    return 1.f - 2.f*__builtin_amdgcn_rcpf(1.f + __expf(2.f*x));
}

// raw barrier: LDS-ordered, does NOT drain vmcnt (global ops stay in flight)
__device__ __forceinline__ void sync_lds(){
    asm volatile("s_waitcnt lgkmcnt(0)\n\ts_barrier" ::: "memory");
}

// ---------------- prep: pack recurrent weights, transpose x-weights, emb->f16, bias ----------
__global__ void prep_kernel(const float* __restrict__ Wr, const float* __restrict__ Wz,
                            const float* __restrict__ Wh, const float* __restrict__ emb,
                            const float* __restrict__ br, const float* __restrict__ bz,
                            const float* __restrict__ bh,
                            uint32_t* __restrict__ wpack, __half* __restrict__ wxt,
                            __half* __restrict__ embf16, float* __restrict__ biasv)
{
    const long long S0 = 2LL*3*128*256;      // packed recurrent h-part weights (h2)
    const long long S1 = 2LL*768*256;        // WxT[L][o][k]
    const long long S2 = 32000LL*256;        // emb f16
    const long long S3 = 2LL*768;            // biasv[L][o]
    for (long long idx = (long long)blockIdx.x*256 + threadIdx.x; idx < S0+S1+S2+S3;
         idx += (long long)gridDim.x*256) {
        if (idx < S0) {
            int n   = (int)(idx & 255);
            int kk2 = (int)((idx >> 8) & 127);
            int t   = (int)(idx >> 15);          // 0..5 = L*3+g
            int g = t % 3, L = t / 3;
            const float* Wsrc = (g==0?Wr:(g==1?Wz:Wh)) + (size_t)L*IN2*HID;
            h2_t p;
            p[0] = (_Float16)Wsrc[(256 + 2*kk2)*HID + n];
            p[1] = (_Float16)Wsrc[(257 + 2*kk2)*HID + n];
            wpack[idx] = __builtin_bit_cast(uint32_t, p);
        } else if (idx < S0+S1) {
            int i  = (int)(idx - S0);
            int k  = i & 255;
            int i2 = i >> 8;                     // 0..1535
            int o  = i2 % 768, L = i2 / 768;
            int g  = o >> 8,   n = o & 255;
            const float* Wsrc = (g==0?Wr:(g==1?Wz:Wh)) + (size_t)L*IN2*HID;
            wxt[i] = __float2half(Wsrc[k*HID + n]);   // WxT[L][o][k]
        } else if (idx < S0+S1+S2) {
            int i = (int)(idx - S0 - S1);
            embf16[i] = __float2half(emb[i]);
        } else {
            int i = (int)(idx - S0 - S1 - S2);   // [0, 1536)
            int o = i % 768, L = i / 768;
            int g = o >> 8,  n = o & 255;
            const float* bsrc = (g==0?br:(g==1?bz:bh));
            biasv[i] = bsrc[L*HID + n];
        }
    }
}

// ---------------- x-projection GEMM (both layers in one launch via blockIdx.z) --------------
// packed proj layout: u32 word g*128+nb of a row holds (val[nb], val[nb+128]) for gate g
__global__ __launch_bounds__(256) void gemm_proj(
    const int* __restrict__ tokens, const __half* __restrict__ embf16,
    const __half* __restrict__ h0chunk, const __half* __restrict__ wxt,
    const float* __restrict__ biasv,
    __half* __restrict__ proj0, __half* __restrict__ proj1, int c0, int c1)
{
    const int Lz = blockIdx.z;
    const int c  = Lz ? c1 : c0;
    if (c < 0 || c >= NCH) return;
    __half* proj = Lz ? proj1 : proj0;

    __shared__ uint4 Ald[128*17];
    __shared__ uint4 Bld[64*17];
    const int tid = threadIdx.x;
    const int mt = blockIdx.x, nt = blockIdx.y;
    const int w = tid >> 6, l = tid & 63, lr = l & 15, lk = l >> 4;
    f32x4 acc[2][4] = {};

#pragma unroll 1
    for (int kh = 0; kh < 2; ++kh) {
        if (kh) __syncthreads();
#pragma unroll
        for (int it = 0; it < 8; ++it) {
            int idx = it*256 + tid;
            int row = idx >> 4, u4 = idx & 15;
            int grow = mt*128 + row;
            const __half* src;
            if (Lz == 0) {
                int b = grow >> 8, tl = grow & (CH-1);
                int tok = tokens[(size_t)b*TSEQ + c*CH + tl];
                src = embf16 + (size_t)tok*HID;
            } else {
                src = h0chunk + (size_t)grow*HID;
            }
            Ald[row*17 + u4] = ((const uint4*)(src + kh*128))[u4];
        }
#pragma unroll
        for (int it = 0; it < 4; ++it) {
            int idx = it*256 + tid;
            int col = idx >> 4, u4 = idx & 15;
            const __half* src = wxt + ((size_t)(Lz*768 + nt*64 + col))*HID + kh*128;
            Bld[col*17 + u4] = ((const uint4*)src)[u4];
        }
        __syncthreads();
        const _Float16* A = (const _Float16*)Ald;
        const _Float16* B = (const _Float16*)Bld;
#pragma unroll
        for (int kb = 0; kb < 4; ++kb) {
            int k0 = kb*32;
            f16x8 af[2], bf[4];
#pragma unroll
            for (int fm = 0; fm < 2; ++fm) {
                int row = w*32 + fm*16 + lr;
                af[fm] = *(const f16x8*)(A + row*136 + k0 + lk*8);
            }
#pragma unroll
            for (int fn = 0; fn < 4; ++fn) {
                int col = fn*16 + lr;
                bf[fn] = *(const f16x8*)(B + col*136 + k0 + lk*8);
            }
#pragma unroll
            for (int fm = 0; fm < 2; ++fm)
#pragma unroll
                for (int fn = 0; fn < 4; ++fn)
                    acc[fm][fn] = __builtin_amdgcn_mfma_f32_16x16x32_f16(af[fm], bf[fn], acc[fm][fn], 0,0,0);
        }
    }
#pragma unroll
    for (int fm = 0; fm < 2; ++fm)
#pragma unroll
        for (int fn = 0; fn < 4; ++fn)
#pragma unroll
            for (int q = 0; q < 4; ++q) {
                int row = mt*128 + w*32 + fm*16 + lk*4 + q;
                int col = nt*64 + fn*16 + lr;
                float v = acc[fm][fn][q] + biasv[Lz*768 + col];
                int po = ((col >> 8) << 8) + ((col & 127) << 1) + ((col >> 7) & 1);
                proj[(size_t)row*768 + po] = __float2half(v);
            }
}

// ---------------- fused recurrence: blocks 0-63 = L0 chunk c0, 64-127 = L1 chunk c1 ---------
// thread (k4 = tid&3, nb = tid>>2): neurons {nb, nb+128}, K-quarter k4.
// amdgpu_waves_per_eu(2,2): occupancy pinned at 2 waves/SIMD -> allocator may use up to
// 256 VGPRs -> the 192 weight words STAY RESIDENT (no scratch spill / no reload).
__global__ __launch_bounds__(512)
__attribute__((amdgpu_waves_per_eu(2, 2)))
void rec_fused(
    const uint32_t* __restrict__ wpack,
    const __half* __restrict__ proj0, const __half* __restrict__ proj1,
    __half* __restrict__ h0chunk, float* __restrict__ hstate,
    const float* __restrict__ Wfc, const float* __restrict__ bfc,
    float* __restrict__ out, int c0, int c1)
{
    __shared__ __align__(16) _Float16 s_h[256];
    __shared__ __align__(16) _Float16 s_rh[256];
    __shared__ float s_head[256];

    const int L = blockIdx.x >> 6;
    const int b = blockIdx.x & 63;
    const int c = L ? c1 : c0;
    if (c < 0 || c >= NCH) return;

    const int tid = threadIdx.x;
    const int k4  = tid & 3;
    const int nb  = tid >> 2;            // [0,128)
    const bool wlead = (k4 == 0);

    // weights as raw u32, load order permuted to match rotated LDS reads:
    // reg index i = u*4+j  <->  K-h2 index  k4*32 + ((u+k4)&7)*4 + j
    uint32_t wr_[2][32], wz_[2][32], wh_[2][32];
    {
        const uint32_t* wb = wpack + (size_t)(L*3*128)*256;
#pragma unroll
        for (int u = 0; u < 8; ++u)
#pragma unroll
            for (int j = 0; j < 4; ++j) {
                int i  = u*4 + j;
                int kk = k4*32 + (((u + k4) & 7)*4 + j);
                wr_[0][i] = wb[(      kk)*256 + nb      ];
                wr_[1][i] = wb[(      kk)*256 + nb + 128];
                wz_[0][i] = wb[(128 + kk)*256 + nb      ];
                wz_[1][i] = wb[(128 + kk)*256 + nb + 128];
                wh_[0][i] = wb[(256 + kk)*256 + nb      ];
                wh_[1][i] = wb[(256 + kk)*256 + nb + 128];
            }
    }
    // pin: asm-defined values cannot be rematerialized from memory
#pragma unroll
    for (int i = 0; i < 32; ++i) {
        asm volatile("" : "+v"(wr_[0][i]), "+v"(wr_[1][i]), "+v"(wz_[0][i]),
                          "+v"(wz_[1][i]), "+v"(wh_[0][i]), "+v"(wh_[1][i]));
    }

    float h0f, h1f;
    if (c == 0) { h0f = 0.f; h1f = 0.f; }
    else {
        h0f = hstate[(size_t)(L*NB + b)*HID + nb];
        h1f = hstate[(size_t)(L*NB + b)*HID + nb + 128];
    }
    if (wlead) { s_h[nb] = (_Float16)h0f; s_h[nb+128] = (_Float16)h1f; }
    __syncthreads();

    const uint32_t* prow = (const uint32_t*)((L ? proj1 : proj0) + (size_t)b*CH*768);
    const uint4* hq4  = ((const uint4*)s_h)  + k4*8;   // quarter = 8 uint4 (128B)
    const uint4* rq4  = ((const uint4*)s_rh) + k4*8;

#pragma unroll 1
    for (int tl = 0; tl < CH; ++tl) {
        // packed proj words (issued early; raw barriers don't drain them)
        const uint32_t* pp = prow + (size_t)tl*384;
        uint32_t pj0 = pp[      nb];
        uint32_t pj1 = pp[128 + nb];
        uint32_t pj2 = pp[256 + nb];

        // phase A: r,z over h; rotated b128 reads interleaved with fdot2 (low reg pressure)
        float ar0=0.f, ar1=0.f, az0=0.f, az1=0.f;
#pragma unroll
        for (int u = 0; u < 8; ++u) {
            uint4 hv = hq4[(u + k4) & 7];
            int i = u*4;
            ar0 = __builtin_amdgcn_fdot2(bc_h2(wr_[0][i  ]), bc_h2(hv.x), ar0, false);
            ar1 = __builtin_amdgcn_fdot2(bc_h2(wr_[1][i  ]), bc_h2(hv.x), ar1, false);
            az0 = __builtin_amdgcn_fdot2(bc_h2(wz_[0][i  ]), bc_h2(hv.x), az0, false);
            az1 = __builtin_amdgcn_fdot2(bc_h2(wz_[1][i  ]), bc_h2(hv.x), az1, false);
            ar0 = __builtin_amdgcn_fdot2(bc_h2(wr_[0][i+1]), bc_h2(hv.y), ar0, false);
            ar1 = __builtin_amdgcn_fdot2(bc_h2(wr_[1][i+1]), bc_h2(hv.y), ar1, false);
            az0 = __builtin_amdgcn_fdot2(bc_h2(wz_[0][i+1]), bc_h2(hv.y), az0, false);
            az1 = __builtin_amdgcn_fdot2(bc_h2(wz_[1][i+1]), bc_h2(hv.y), az1, false);
            ar0 = __builtin_amdgcn_fdot2(bc_h2(wr_[0][i+2]), bc_h2(hv.z), ar0, false);
            ar1 = __builtin_amdgcn_fdot2(bc_h2(wr_[1][i+2]), bc_h2(hv.z), ar1, false);
            az0 = __builtin_amdgcn_fdot2(bc_h2(wz_[0][i+2]), bc_h2(hv.z), az0, false);
            az1 = __builtin_amdgcn_fdot2(bc_h2(wz_[1][i+2]), bc_h2(hv.z), az1, false);
            ar0 = __builtin_amdgcn_fdot2(bc_h2(wr_[0][i+3]), bc_h2(hv.w), ar0, false);
            ar1 = __builtin_amdgcn_fdot2(bc_h2(wr_[1][i+3]), bc_h2(hv.w), ar1, false);
            az0 = __builtin_amdgcn_fdot2(bc_h2(wz_[0][i+3]), bc_h2(hv.w), az0, false);
            az1 = __builtin_amdgcn_fdot2(bc_h2(wz_[1][i+3]), bc_h2(hv.w), az1, false);
        }
        ar0 = quad_reduce(ar0); ar1 = quad_reduce(ar1);
        az0 = quad_reduce(az0); az1 = quad_reduce(az1);

        h2_t pjr = bc_h2(pj0), pjz = bc_h2(pj1);
        float r0 = sigm_(ar0 + (float)pjr[0]);
        float r1 = sigm_(ar1 + (float)pjr[1]);
        float z0 = sigm_(az0 + (float)pjz[0]);
        float z1 = sigm_(az1 + (float)pjz[1]);
        if (wlead) { s_rh[nb] = (_Float16)(r0*h0f); s_rh[nb+128] = (_Float16)(r1*h1f); }
        sync_lds();

        // phase B: candidate over r*h; same rotation, interleaved reads
        float ah0a=0.f, ah0b=0.f, ah1a=0.f, ah1b=0.f;
#pragma unroll
        for (int u = 0; u < 8; ++u) {
            uint4 rv = rq4[(u + k4) & 7];
            int i = u*4;
            ah0a = __builtin_amdgcn_fdot2(bc_h2(wh_[0][i  ]), bc_h2(rv.x), ah0a, false);
            ah1a = __builtin_amdgcn_fdot2(bc_h2(wh_[1][i  ]), bc_h2(rv.x), ah1a, false);
            ah0b = __builtin_amdgcn_fdot2(bc_h2(wh_[0][i+1]), bc_h2(rv.y), ah0b, false);
            ah1b = __builtin_amdgcn_fdot2(bc_h2(wh_[1][i+1]), bc_h2(rv.y), ah1b, false);
            ah0a = __builtin_amdgcn_fdot2(bc_h2(wh_[0][i+2]), bc_h2(rv.z), ah0a, false);
            ah1a = __builtin_amdgcn_fdot2(bc_h2(wh_[1][i+2]), bc_h2(rv.z), ah1a, false);
            ah0b = __builtin_amdgcn_fdot2(bc_h2(wh_[0][i+3]), bc_h2(rv.w), ah0b, false);
            ah1b = __builtin_amdgcn_fdot2(bc_h2(wh_[1][i+3]), bc_h2(rv.w), ah1b, false);
        }
        float ah0 = quad_reduce(ah0a + ah0b);
        float ah1 = quad_reduce(ah1a + ah1b);

        h2_t pjh = bc_h2(pj2);
        float t0 = tanh_(ah0 + (float)pjh[0]);
        float t1 = tanh_(ah1 + (float)pjh[1]);
        h0f += z0*(t0 - h0f);
        h1f += z1*(t1 - h1f);
        if (wlead) {
            s_h[nb]     = (_Float16)h0f;
            s_h[nb+128] = (_Float16)h1f;
            if (L == 0) {
                __half* hc = h0chunk + ((size_t)b*CH + tl)*HID;
                hc[nb]     = __float2half(h0f);
                hc[nb+128] = __float2half(h1f);
            }
        }
        sync_lds();
    }

    if (wlead) {
        hstate[(size_t)(L*NB + b)*HID + nb]       = h0f;
        hstate[(size_t)(L*NB + b)*HID + nb + 128] = h1f;
    }

    if (L == 1 && c == NCH-1) {
        if (wlead) { s_head[nb] = h0f; s_head[nb+128] = h1f; }
        __syncthreads();
        if (tid < 64) {
            float p0 = 0.f, p1 = 0.f;
#pragma unroll
            for (int m = 0; m < 4; ++m) {
                float hv2 = s_head[tid + 64*m];
                p0 += hv2 * Wfc[(tid+64*m)*2+0];
                p1 += hv2 * Wfc[(tid+64*m)*2+1];
            }
#pragma unroll
            for (int d = 1; d < 64; d <<= 1) { p0 += __shfl_xor(p0, d); p1 += __shfl_xor(p1, d); }
            if (tid == 0) { out[b*2+0] = p0 + bfc[0]; out[b*2+1] = p1 + bfc[1]; }
        }
    }
}

// ---------------- host ----------------
extern "C" void kernel_launch(void* const* d_in, const int* in_sizes, int n_in,
                              void* d_out, int out_size, void* d_ws, size_t ws_size,
                              hipStream_t stream) {
    const int*   tokens = (const int*)  d_in[0];
    const float* emb    = (const float*)d_in[1];
    const float* Wr     = (const float*)d_in[2];
    const float* br     = (const float*)d_in[3];
    const float* Wz     = (const float*)d_in[4];
    const float* bz     = (const float*)d_in[5];
    const float* Wh     = (const float*)d_in[6];
    const float* bh     = (const float*)d_in[7];
    const float* Wfc    = (const float*)d_in[8];
    const float* bfc    = (const float*)d_in[9];
    float* out = (float*)d_out;

    char* ws = (char*)d_ws;
    uint32_t* wpack  = (uint32_t*)(ws + 0);               //   786,432 B
    __half*   wxt    = (__half*)(ws + (1u<<20));          //   786,432 B
    __half*   embf16 = (__half*)(ws + (2u<<20));          // 16,384,000 B
    __half*   proj0  = (__half*)(ws + 18874368u);         // 25,165,824 B
    __half*   proj1  = (__half*)(ws + 44040192u);         // 25,165,824 B
    __half*   h0chunk= (__half*)(ws + 69206016u);         //  8,388,608 B
    float*    hstate = (float*)(ws + 77594624u);          //    131,072 B
    float*    biasv  = (float*)(ws + 77725696u);          //      6,144 B

    prep_kernel<<<2048, 256, 0, stream>>>(Wr, Wz, Wh, emb, br, bz, bh, wpack, wxt, embf16, biasv);

    dim3 ggrid(128, 12, 2);
    for (int c = 0; c <= NCH; ++c) {
        int cc0 = (c < NCH) ? c : -1;
        int cc1 = c - 1;
        gemm_proj<<<ggrid, 256, 0, stream>>>(tokens, embf16, h0chunk, wxt, biasv, proj0, proj1, cc0, cc1);
        rec_fused<<<128, 512, 0, stream>>>(wpack, proj0, proj1, h0chunk, hstate, Wfc, bfc, out, cc0, cc1);
    }
}

// Round 10
// 7010.670 us; speedup vs baseline: 1.4537x; 1.0596x over previous
//
#include <hip/hip_runtime.h>
#include <hip/hip_bf16.h>
#include <hip/hip_fp16.h>
#include <stdint.h>

typedef _Float16 h2_t  __attribute__((ext_vector_type(2)));
typedef _Float16 f16x8 __attribute__((ext_vector_type(8)));
typedef float    f32x4 __attribute__((ext_vector_type(4)));

#define TSEQ 4096
#define HID  256
#define IN2  512
#define NB   64
#define CH   256
#define NCH  16

__device__ __forceinline__ h2_t bc_h2(uint32_t v){ return __builtin_bit_cast(h2_t, v); }
__device__ __forceinline__ uint32_t pk2(float a, float b){
    h2_t p; p[0] = (_Float16)a; p[1] = (_Float16)b;
    return __builtin_bit_cast(uint32_t, p);
}

// quad butterfly reduce via DPP (VALU pipe, not LDS)
__device__ __forceinline__ float quad_reduce(float x){
    float t;
    t = __builtin_bit_cast(float, __builtin_amdgcn_mov_dpp(__builtin_bit_cast(int, x), 0xB1, 0xF, 0xF, true));
    x += t;
    t = __builtin_bit_cast(float, __builtin_amdgcn_mov_dpp(__builtin_bit_cast(int, x), 0x4E, 0xF, 0xF, true));
    x += t;
    return x;
}

// cheap activations (validated r6-r9: absmax unchanged)
__device__ __forceinline__ float sigm_(float x){
    return __builtin_amdgcn_rcpf(1.f + __expf(-x));
}
__device__ __forceinline__ float tanh_(float x){
    return 1.f - 2.f*__builtin_amdgcn_rcpf(1.f + __expf(2.f*x));
}

// raw barrier: LDS-ordered, does NOT drain vmcnt (global ops stay in flight)
__device__ __forceinline__ void sync_lds(){
    asm volatile("s_waitcnt lgkmcnt(0)\n\ts_barrier" ::: "memory");
}

// ---------------- prep ---------------------------------------------------------------------
// wpack word (g, kk, n), kk in [0,128): ( W[256+kk][n], W[256+128+kk][n] ) as f16 pair.
//   -> matches pair-packed s_h layout: word j = (h[j], h[j+128]).
// wxt[L][o][k]: L0: k = emb dim (unpermuted). L1: k-dim permuted with pi(k) = (k&1)?128+(k>>1):(k>>1)
//   to match the pair-interleaved h0chunk rows.
__global__ void prep_kernel(const float* __restrict__ Wr, const float* __restrict__ Wz,
                            const float* __restrict__ Wh, const float* __restrict__ emb,
                            const float* __restrict__ br, const float* __restrict__ bz,
                            const float* __restrict__ bh,
                            uint32_t* __restrict__ wpack, __half* __restrict__ wxt,
                            __half* __restrict__ embf16, float* __restrict__ biasv)
{
    const long long S0 = 2LL*3*128*256;
    const long long S1 = 2LL*768*256;
    const long long S2 = 32000LL*256;
    const long long S3 = 2LL*768;
    for (long long idx = (long long)blockIdx.x*256 + threadIdx.x; idx < S0+S1+S2+S3;
         idx += (long long)gridDim.x*256) {
        if (idx < S0) {
            int n   = (int)(idx & 255);
            int kk  = (int)((idx >> 8) & 127);
            int t   = (int)(idx >> 15);          // 0..5 = L*3+g
            int g = t % 3, L = t / 3;
            const float* Wsrc = (g==0?Wr:(g==1?Wz:Wh)) + (size_t)L*IN2*HID;
            h2_t p;
            p[0] = (_Float16)Wsrc[(256 + kk)*HID + n];
            p[1] = (_Float16)Wsrc[(256 + 128 + kk)*HID + n];
            wpack[idx] = __builtin_bit_cast(uint32_t, p);
        } else if (idx < S0+S1) {
            int i  = (int)(idx - S0);
            int k  = i & 255;
            int i2 = i >> 8;                     // 0..1535
            int o  = i2 % 768, L = i2 / 768;
            int g  = o >> 8,   n = o & 255;
            const float* Wsrc = (g==0?Wr:(g==1?Wz:Wh)) + (size_t)L*IN2*HID;
            int ksrc = (L==1) ? ((k & 1) ? 128 + (k >> 1) : (k >> 1)) : k;
            wxt[i] = __float2half(Wsrc[ksrc*HID + n]);
        } else if (idx < S0+S1+S2) {
            int i = (int)(idx - S0 - S1);
            embf16[i] = __float2half(emb[i]);
        } else {
            int i = (int)(idx - S0 - S1 - S2);   // [0, 1536)
            int o = i % 768, L = i / 768;
            int g = o >> 8,  n = o & 255;
            const float* bsrc = (g==0?br:(g==1?bz:bh));
            biasv[i] = bsrc[L*HID + n];
        }
    }
}

// ---------------- x-projection GEMM --------------------------------------------------------
// proj row layout (per sample-row, 2048 B): 128 x uint4; entry nb =
//   { (r_nb,r_nb+128), (z_nb,z_nb+128), (h_nb,h_nb+128), pad } as f16 pairs.
__global__ __launch_bounds__(256) void gemm_proj(
    const int* __restrict__ tokens, const __half* __restrict__ embf16,
    const __half* __restrict__ h0chunk, const __half* __restrict__ wxt,
    const float* __restrict__ biasv,
    __half* __restrict__ proj0, __half* __restrict__ proj1, int c0, int c1)
{
    const int Lz = blockIdx.z;
    const int c  = Lz ? c1 : c0;
    if (c < 0 || c >= NCH) return;
    __half* proj = Lz ? proj1 : proj0;

    __shared__ uint4 Ald[128*17];
    __shared__ uint4 Bld[64*17];
    const int tid = threadIdx.x;
    const int mt = blockIdx.x, nt = blockIdx.y;
    const int w = tid >> 6, l = tid & 63, lr = l & 15, lk = l >> 4;
    f32x4 acc[2][4] = {};

#pragma unroll 1
    for (int kh = 0; kh < 2; ++kh) {
        if (kh) __syncthreads();
#pragma unroll
        for (int it = 0; it < 8; ++it) {
            int idx = it*256 + tid;
            int row = idx >> 4, u4 = idx & 15;
            int grow = mt*128 + row;
            const __half* src;
            if (Lz == 0) {
                int b = grow >> 8, tl = grow & (CH-1);
                int tok = tokens[(size_t)b*TSEQ + c*CH + tl];
                src = embf16 + (size_t)tok*HID;
            } else {
                src = h0chunk + (size_t)grow*HID;
            }
            Ald[row*17 + u4] = ((const uint4*)(src + kh*128))[u4];
        }
#pragma unroll
        for (int it = 0; it < 4; ++it) {
            int idx = it*256 + tid;
            int col = idx >> 4, u4 = idx & 15;
            const __half* src = wxt + ((size_t)(Lz*768 + nt*64 + col))*HID + kh*128;
            Bld[col*17 + u4] = ((const uint4*)src)[u4];
        }
        __syncthreads();
        const _Float16* A = (const _Float16*)Ald;
        const _Float16* B = (const _Float16*)Bld;
#pragma unroll
        for (int kb = 0; kb < 4; ++kb) {
            int k0 = kb*32;
            f16x8 af[2], bf[4];
#pragma unroll
            for (int fm = 0; fm < 2; ++fm) {
                int row = w*32 + fm*16 + lr;
                af[fm] = *(const f16x8*)(A + row*136 + k0 + lk*8);
            }
#pragma unroll
            for (int fn = 0; fn < 4; ++fn) {
                int col = fn*16 + lr;
                bf[fn] = *(const f16x8*)(B + col*136 + k0 + lk*8);
            }
#pragma unroll
            for (int fm = 0; fm < 2; ++fm)
#pragma unroll
                for (int fn = 0; fn < 4; ++fn)
                    acc[fm][fn] = __builtin_amdgcn_mfma_f32_16x16x32_f16(af[fm], bf[fn], acc[fm][fn], 0,0,0);
        }
    }
#pragma unroll
    for (int fm = 0; fm < 2; ++fm)
#pragma unroll
        for (int fn = 0; fn < 4; ++fn)
#pragma unroll
            for (int q = 0; q < 4; ++q) {
                int row = mt*128 + w*32 + fm*16 + lk*4 + q;
                int col = nt*64 + fn*16 + lr;
                float v = acc[fm][fn][q] + biasv[Lz*768 + col];
                int nb2 = col & 127, g = col >> 8, hf2 = (col >> 7) & 1;
                proj[(size_t)row*1024 + nb2*8 + g*2 + hf2] = __float2half(v);
            }
}

// ---------------- fused recurrence: blocks 0-63 = L0 chunk c0, 64-127 = L1 chunk c1 ---------
// thread (k4 = tid&3, nb = tid>>2): neurons {nb, nb+128}, K-quarter k4.
// Pair-packed LDS state (u32 per neuron pair); packed proj uint4 with next-step prefetch.
__global__ __launch_bounds__(512)
__attribute__((amdgpu_waves_per_eu(2, 2)))
void rec_fused(
    const uint32_t* __restrict__ wpack,
    const __half* __restrict__ proj0, const __half* __restrict__ proj1,
    __half* __restrict__ h0chunk, float* __restrict__ hstate,
    const float* __restrict__ Wfc, const float* __restrict__ bfc,
    float* __restrict__ out, int c0, int c1)
{
    __shared__ __align__(16) uint32_t s_h[128];    // word j = (h[j], h[j+128]) f16
    __shared__ __align__(16) uint32_t s_rh[128];
    __shared__ float s_head[256];

    const int L = blockIdx.x >> 6;
    const int b = blockIdx.x & 63;
    const int c = L ? c1 : c0;
    if (c < 0 || c >= NCH) return;

    const int tid = threadIdx.x;
    const int k4  = tid & 3;
    const int nb  = tid >> 2;            // [0,128)
    const bool wlead = (k4 == 0);

    // weights, rotation-permuted: reg i = u*4+j <-> pair-word kk = k4*32 + ((u+k4)&7)*4 + j
    uint32_t wr_[2][32], wz_[2][32], wh_[2][32];
    {
        const uint32_t* wb = wpack + (size_t)(L*3*128)*256;
#pragma unroll
        for (int u = 0; u < 8; ++u)
#pragma unroll
            for (int j = 0; j < 4; ++j) {
                int i  = u*4 + j;
                int kk = k4*32 + (((u + k4) & 7)*4 + j);
                wr_[0][i] = wb[(      kk)*256 + nb      ];
                wr_[1][i] = wb[(      kk)*256 + nb + 128];
                wz_[0][i] = wb[(128 + kk)*256 + nb      ];
                wz_[1][i] = wb[(128 + kk)*256 + nb + 128];
                wh_[0][i] = wb[(256 + kk)*256 + nb      ];
                wh_[1][i] = wb[(256 + kk)*256 + nb + 128];
            }
    }
#pragma unroll
    for (int i = 0; i < 32; ++i) {
        asm volatile("" : "+v"(wr_[0][i]), "+v"(wr_[1][i]), "+v"(wz_[0][i]),
                          "+v"(wz_[1][i]), "+v"(wh_[0][i]), "+v"(wh_[1][i]));
    }

    float h0f, h1f;
    if (c == 0) { h0f = 0.f; h1f = 0.f; }
    else {
        h0f = hstate[(size_t)(L*NB + b)*HID + nb];
        h1f = hstate[(size_t)(L*NB + b)*HID + nb + 128];
    }
    if (wlead) s_h[nb] = pk2(h0f, h1f);
    __syncthreads();

    const uint4* prow = (const uint4*)((L ? proj1 : proj0) + (size_t)b*CH*1024);
    const uint4* hq4  = ((const uint4*)s_h)  + k4*8;   // quarter = 8 uint4 (128B)
    const uint4* rq4  = ((const uint4*)s_rh) + k4*8;

    uint4 pj = prow[nb];     // step-0 proj (r,z,h packed pairs)

#pragma unroll 1
    for (int tl = 0; tl < CH; ++tl) {
        // prefetch next step's packed proj (raw barriers keep it in flight)
        int tn = (tl + 1 < CH) ? tl + 1 : tl;
        uint4 pjN = prow[(size_t)tn*128 + nb];

        // phase A: r,z over h; rotated b128 reads (conflict-free across k4)
        float ar0=0.f, ar1=0.f, az0=0.f, az1=0.f;
#pragma unroll
        for (int u = 0; u < 8; ++u) {
            uint4 hv = hq4[(u + k4) & 7];
            int i = u*4;
            ar0 = __builtin_amdgcn_fdot2(bc_h2(wr_[0][i  ]), bc_h2(hv.x), ar0, false);
            ar1 = __builtin_amdgcn_fdot2(bc_h2(wr_[1][i  ]), bc_h2(hv.x), ar1, false);
            az0 = __builtin_amdgcn_fdot2(bc_h2(wz_[0][i  ]), bc_h2(hv.x), az0, false);
            az1 = __builtin_amdgcn_fdot2(bc_h2(wz_[1][i  ]), bc_h2(hv.x), az1, false);
            ar0 = __builtin_amdgcn_fdot2(bc_h2(wr_[0][i+1]), bc_h2(hv.y), ar0, false);
            ar1 = __builtin_amdgcn_fdot2(bc_h2(wr_[1][i+1]), bc_h2(hv.y), ar1, false);
            az0 = __builtin_amdgcn_fdot2(bc_h2(wz_[0][i+1]), bc_h2(hv.y), az0, false);
            az1 = __builtin_amdgcn_fdot2(bc_h2(wz_[1][i+1]), bc_h2(hv.y), az1, false);
            ar0 = __builtin_amdgcn_fdot2(bc_h2(wr_[0][i+2]), bc_h2(hv.z), ar0, false);
            ar1 = __builtin_amdgcn_fdot2(bc_h2(wr_[1][i+2]), bc_h2(hv.z), ar1, false);
            az0 = __builtin_amdgcn_fdot2(bc_h2(wz_[0][i+2]), bc_h2(hv.z), az0, false);
            az1 = __builtin_amdgcn_fdot2(bc_h2(wz_[1][i+2]), bc_h2(hv.z), az1, false);
            ar0 = __builtin_amdgcn_fdot2(bc_h2(wr_[0][i+3]), bc_h2(hv.w), ar0, false);
            ar1 = __builtin_amdgcn_fdot2(bc_h2(wr_[1][i+3]), bc_h2(hv.w), ar1, false);
            az0 = __builtin_amdgcn_fdot2(bc_h2(wz_[0][i+3]), bc_h2(hv.w), az0, false);
            az1 = __builtin_amdgcn_fdot2(bc_h2(wz_[1][i+3]), bc_h2(hv.w), az1, false);
        }
        ar0 = quad_reduce(ar0); ar1 = quad_reduce(ar1);
        az0 = quad_reduce(az0); az1 = quad_reduce(az1);

        h2_t pjr = bc_h2(pj.x), pjz = bc_h2(pj.y);
        float r0 = sigm_(ar0 + (float)pjr[0]);
        float r1 = sigm_(ar1 + (float)pjr[1]);
        float z0 = sigm_(az0 + (float)pjz[0]);
        float z1 = sigm_(az1 + (float)pjz[1]);
        if (wlead) s_rh[nb] = pk2(r0*h0f, r1*h1f);
        sync_lds();

        // phase B: candidate over r*h; same rotation
        float ah0a=0.f, ah0b=0.f, ah1a=0.f, ah1b=0.f;
#pragma unroll
        for (int u = 0; u < 8; ++u) {
            uint4 rv = rq4[(u + k4) & 7];
            int i = u*4;
            ah0a = __builtin_amdgcn_fdot2(bc_h2(wh_[0][i  ]), bc_h2(rv.x), ah0a, false);
            ah1a = __builtin_amdgcn_fdot2(bc_h2(wh_[1][i  ]), bc_h2(rv.x), ah1a, false);
            ah0b = __builtin_amdgcn_fdot2(bc_h2(wh_[0][i+1]), bc_h2(rv.y), ah0b, false);
            ah1b = __builtin_amdgcn_fdot2(bc_h2(wh_[1][i+1]), bc_h2(rv.y), ah1b, false);
            ah0a = __builtin_amdgcn_fdot2(bc_h2(wh_[0][i+2]), bc_h2(rv.z), ah0a, false);
            ah1a = __builtin_amdgcn_fdot2(bc_h2(wh_[1][i+2]), bc_h2(rv.z), ah1a, false);
            ah0b = __builtin_amdgcn_fdot2(bc_h2(wh_[0][i+3]), bc_h2(rv.w), ah0b, false);
            ah1b = __builtin_amdgcn_fdot2(bc_h2(wh_[1][i+3]), bc_h2(rv.w), ah1b, false);
        }
        float ah0 = quad_reduce(ah0a + ah0b);
        float ah1 = quad_reduce(ah1a + ah1b);

        h2_t pjh = bc_h2(pj.z);
        float t0 = tanh_(ah0 + (float)pjh[0]);
        float t1 = tanh_(ah1 + (float)pjh[1]);
        h0f += z0*(t0 - h0f);
        h1f += z1*(t1 - h1f);
        if (wlead) {
            uint32_t w2 = pk2(h0f, h1f);
            s_h[nb] = w2;
            if (L == 0)
                ((uint32_t*)h0chunk)[((size_t)b*CH + tl)*128 + nb] = w2;
        }
        pj = pjN;
        sync_lds();
    }

    if (wlead) {
        hstate[(size_t)(L*NB + b)*HID + nb]       = h0f;
        hstate[(size_t)(L*NB + b)*HID + nb + 128] = h1f;
    }

    if (L == 1 && c == NCH-1) {
        if (wlead) { s_head[nb] = h0f; s_head[nb+128] = h1f; }
        __syncthreads();
        if (tid < 64) {
            float p0 = 0.f, p1 = 0.f;
#pragma unroll
            for (int m = 0; m < 4; ++m) {
                float hv2 = s_head[tid + 64*m];
                p0 += hv2 * Wfc[(tid+64*m)*2+0];
                p1 += hv2 * Wfc[(tid+64*m)*2+1];
            }
#pragma unroll
            for (int d = 1; d < 64; d <<= 1) { p0 += __shfl_xor(p0, d); p1 += __shfl_xor(p1, d); }
            if (tid == 0) { out[b*2+0] = p0 + bfc[0]; out[b*2+1] = p1 + bfc[1]; }
        }
    }
}

// ---------------- host ----------------
extern "C" void kernel_launch(void* const* d_in, const int* in_sizes, int n_in,
                              void* d_out, int out_size, void* d_ws, size_t ws_size,
                              hipStream_t stream) {
    const int*   tokens = (const int*)  d_in[0];
    const float* emb    = (const float*)d_in[1];
    const float* Wr     = (const float*)d_in[2];
    const float* br     = (const float*)d_in[3];
    const float* Wz     = (const float*)d_in[4];
    const float* bz     = (const float*)d_in[5];
    const float* Wh     = (const float*)d_in[6];
    const float* bh     = (const float*)d_in[7];
    const float* Wfc    = (const float*)d_in[8];
    const float* bfc    = (const float*)d_in[9];
    float* out = (float*)d_out;

    char* ws = (char*)d_ws;
    uint32_t* wpack  = (uint32_t*)(ws + 0);               //    786,432 B
    __half*   wxt    = (__half*)(ws + (1u<<20));          //    786,432 B
    __half*   embf16 = (__half*)(ws + (2u<<20));          // 16,384,000 B
    __half*   proj0  = (__half*)(ws + 18874368u);         // 33,554,432 B (16384 x 2048B)
    __half*   proj1  = (__half*)(ws + 52428800u);         // 33,554,432 B
    __half*   h0chunk= (__half*)(ws + 85983232u);         //  8,388,608 B
    float*    hstate = (float*)(ws + 94371840u);          //    131,072 B
    float*    biasv  = (float*)(ws + 94502912u);          //      6,144 B  (~90.1 MB total)

    prep_kernel<<<2048, 256, 0, stream>>>(Wr, Wz, Wh, emb, br, bz, bh, wpack, wxt, embf16, biasv);

    dim3 ggrid(128, 12, 2);
    for (int c = 0; c <= NCH; ++c) {
        int cc0 = (c < NCH) ? c : -1;
        int cc1 = c - 1;
        gemm_proj<<<ggrid, 256, 0, stream>>>(tokens, embf16, h0chunk, wxt, biasv, proj0, proj1, cc0, cc1);
        rec_fused<<<128, 512, 0, stream>>>(wpack, proj0, proj1, h0chunk, hstate, Wfc, bfc, out, cc0, cc1);
    }
}